// Round 4
// baseline (3102.558 us; speedup 1.0000x reference)
//
#include <hip/hip_runtime.h>

typedef unsigned short u16;
typedef unsigned int u32;
typedef __attribute__((ext_vector_type(8))) short short8;
typedef __attribute__((ext_vector_type(8))) u16 ushort8;
typedef __attribute__((ext_vector_type(4))) u16 ushort4_t;
typedef __attribute__((ext_vector_type(4))) float fx4;

#define DIMK 2048
#define NBLK 2000

typedef const __attribute__((address_space(1))) void* gp_t;
typedef __attribute__((address_space(3))) void* lp_t;

__device__ __forceinline__ u16 f2bf(float f) {
  u32 u = __float_as_uint(f);
  u32 r = (u + 0x7fffu + ((u >> 16) & 1u)) >> 16;
  return (u16)r;
}

__device__ __forceinline__ u32 fkey(float f) {
  u32 u = __float_as_uint(f);
  return (u & 0x80000000u) ? ~u : (u | 0x80000000u);
}
__device__ __forceinline__ float dekey(u32 k) {
  u32 u = (k & 0x80000000u) ? (k ^ 0x80000000u) : ~k;
  return __uint_as_float(u);
}

// ---------------------------------------------------------------------------
// Legacy 128x128 tile (kept for gram_kernel). Zero-conflict XOR granule
// swizzle, verified SQ_LDS_BANK_CONFLICT == 0.
// ---------------------------------------------------------------------------
__device__ __forceinline__ void gemm_tile(const u16* __restrict__ Abase,
                                          const u16* __restrict__ Bbase,
                                          int row0, int col0,
                                          u16* lsA, u16* lsB,
                                          fx4 acc[4][4])
{
  const int tid  = threadIdx.x;
  const int wv   = tid >> 6;
  const int lane = tid & 63;
  const int wr   = wv & 1, wc = wv >> 1;
  const int quad = lane >> 4, lc = lane & 15;

  const int srow = wv * 32 + (lane >> 2);
  const int skel = (((lane & 3) ^ ((lane >> 3) & 3)) * 8);
  const u16* gA0 = Abase + (size_t)(row0 + srow) * DIMK + skel;
  const u16* gA1 = gA0 + (size_t)16 * DIMK;
  const u16* gB0 = Bbase + (size_t)(col0 + srow) * DIMK + skel;
  const u16* gB1 = gB0 + (size_t)16 * DIMK;
  u16* lA0 = lsA + wv * 1024;
  u16* lA1 = lsA + wv * 1024 + 512;
  u16* lB0 = lsB + wv * 1024;
  u16* lB1 = lsB + wv * 1024 + 512;

  const int fIntra = lc * 32 + ((quad ^ ((lc >> 1) & 3)) * 8);

#pragma unroll
  for (int mi = 0; mi < 4; mi++)
#pragma unroll
    for (int ni = 0; ni < 4; ni++)
      acc[mi][ni] = fx4{0.f, 0.f, 0.f, 0.f};

  for (int k0 = 0; k0 < DIMK; k0 += 32) {
    __syncthreads();
    __builtin_amdgcn_global_load_lds((gp_t)gA0, (lp_t)lA0, 16, 0, 0);
    __builtin_amdgcn_global_load_lds((gp_t)gA1, (lp_t)lA1, 16, 0, 0);
    __builtin_amdgcn_global_load_lds((gp_t)gB0, (lp_t)lB0, 16, 0, 0);
    __builtin_amdgcn_global_load_lds((gp_t)gB1, (lp_t)lB1, 16, 0, 0);
    gA0 += 32; gA1 += 32; gB0 += 32; gB1 += 32;
    __syncthreads();
    short8 af[4], bfr[4];
#pragma unroll
    for (int mi = 0; mi < 4; mi++)
      af[mi] = *(const short8*)(lsA + (wr * 4 + mi) * 512 + fIntra);
#pragma unroll
    for (int ni = 0; ni < 4; ni++)
      bfr[ni] = *(const short8*)(lsB + (wc * 4 + ni) * 512 + fIntra);
#pragma unroll
    for (int mi = 0; mi < 4; mi++)
#pragma unroll
      for (int ni = 0; ni < 4; ni++)
        acc[mi][ni] = __builtin_amdgcn_mfma_f32_16x16x32_bf16(af[mi], bfr[ni], acc[mi][ni], 0, 0, 0);
  }
}

// one wave per row; block = 4 waves = 4 rows. No LDS, no __syncthreads.
__global__ __launch_bounds__(256) void norm_rows_x(const float* __restrict__ x,
                                                   u16* __restrict__ Xn)
{
  const int wv = threadIdx.x >> 6, lane = threadIdx.x & 63;
  const int row = blockIdx.x * 4 + wv;
  const float4* xr = (const float4*)(x + (size_t)row * DIMK);
  float4 v[8];
  float ss = 0.f;
#pragma unroll
  for (int j = 0; j < 8; j++) {
    v[j] = xr[j * 64 + lane];
    ss += v[j].x*v[j].x + v[j].y*v[j].y + v[j].z*v[j].z + v[j].w*v[j].w;
  }
#pragma unroll
  for (int off = 1; off < 64; off <<= 1) ss += __shfl_xor(ss, off);
  float inv = 1.0f / fmaxf(sqrtf(ss), 1e-12f);
  ushort4_t* o = (ushort4_t*)(Xn + (size_t)row * DIMK);
#pragma unroll
  for (int j = 0; j < 8; j++) {
    ushort4_t t;
    t[0] = f2bf(v[j].x * inv); t[1] = f2bf(v[j].y * inv);
    t[2] = f2bf(v[j].z * inv); t[3] = f2bf(v[j].w * inv);
    o[j * 64 + lane] = t;
  }
}

__global__ __launch_bounds__(256) void norm_rows_w(const float* __restrict__ w,
                                                   u16* __restrict__ Wn,
                                                   u16* __restrict__ Wb)
{
  const int wv = threadIdx.x >> 6, lane = threadIdx.x & 63;
  const int row = blockIdx.x * 4 + wv;
  ushort4_t* on_ = (ushort4_t*)(Wn + (size_t)row * DIMK);
  ushort4_t* ob_ = (ushort4_t*)(Wb + (size_t)row * DIMK);
  if (row < NBLK) {
    const float4* wr_ = (const float4*)(w + (size_t)row * DIMK);
    float4 v[8];
    float ss = 0.f;
#pragma unroll
    for (int j = 0; j < 8; j++) {
      v[j] = wr_[j * 64 + lane];
      ss += v[j].x*v[j].x + v[j].y*v[j].y + v[j].z*v[j].z + v[j].w*v[j].w;
    }
#pragma unroll
    for (int off = 1; off < 64; off <<= 1) ss += __shfl_xor(ss, off);
    float inv = 1.0f / fmaxf(sqrtf(ss), 1e-12f);
#pragma unroll
    for (int j = 0; j < 8; j++) {
      ushort4_t tn, tb;
      tn[0] = f2bf(v[j].x * inv); tn[1] = f2bf(v[j].y * inv);
      tn[2] = f2bf(v[j].z * inv); tn[3] = f2bf(v[j].w * inv);
      tb[0] = f2bf(v[j].x); tb[1] = f2bf(v[j].y);
      tb[2] = f2bf(v[j].z); tb[3] = f2bf(v[j].w);
      on_[j * 64 + lane] = tn;
      ob_[j * 64 + lane] = tb;
    }
  } else {
    ushort4_t z = ushort4_t{0, 0, 0, 0};
#pragma unroll
    for (int j = 0; j < 8; j++) { on_[j * 64 + lane] = z; ob_[j * 64 + lane] = z; }
  }
}

// Gram is symmetric: compute only tiles with by <= bx; off-diagonal tiles
// contribute twice. Blocks with by > bx exit immediately (uniform branch,
// before any barrier).
__global__ __launch_bounds__(256) void gram_kernel(const u16* __restrict__ Wb,
                                                   float* __restrict__ divsum)
{
  const int bx = blockIdx.x, by = blockIdx.y;
  if (by > bx) return;
  __shared__ __align__(16) u16 lsA[4096];
  __shared__ __align__(16) u16 lsB[4096];
  fx4 acc[4][4];
  const int i0 = by * 128, j0 = bx * 128;
  gemm_tile(Wb, Wb, i0, j0, lsA, lsB, acc);
  const int tid = threadIdx.x, wv = tid >> 6, lane = tid & 63;
  const int wr = wv & 1, wc = wv >> 1, quad = lane >> 4, lc = lane & 15;
  const float mult = (bx == by) ? 1.0f : 2.0f;
  float local = 0.f;
#pragma unroll
  for (int mi = 0; mi < 4; mi++) {
#pragma unroll
    for (int ni = 0; ni < 4; ni++) {
#pragma unroll
      for (int r = 0; r < 4; r++) {
        int i = i0 + wr * 64 + mi * 16 + quad * 4 + r;
        int j = j0 + wc * 64 + ni * 16 + lc;
        float g = acc[mi][ni][r];
        float d = (i == j && i < NBLK) ? 1.0f : 0.0f;
        float e = g - d;
        local += e * e;
      }
    }
  }
  local *= mult;
#pragma unroll
  for (int off = 1; off < 64; off <<= 1) local += __shfl_xor(local, off);
  if (lane == 0) atomicAdd(divsum, local);
}

// ---------------------------------------------------------------------------
// att: 256x256 tile, 8 waves (2M x 4N, 128x64 per wave), BK=32.
// r4 change: 2-slot double buffer (64 KB LDS) so TWO blocks co-reside per CU
// (__launch_bounds__(512,4)). Rationale (r3 post-mortem): MFMA issue blocks
// the wave, so within one barrier-synced block the LDS phase and MFMA phase
// are structurally serial (measured 2812 cyc/step = 1152 LDS + 1242 MFMA +
// slop, MfmaUtil 40%, Occupancy 22% = 1 block/CU, LDS-limited at 128 KB).
// Cross-BLOCK overlap (m114: independent waves' MFMA and LDS co-schedule
// fully) needs a second block: 64 KB x 2 fits 160 KB. Single-phase K-step
// (r1 structure, proven correct at 293 us): 2 barriers/step, prefetch
// distance 1, vmcnt(4) steady / vmcnt(0) tail.
// Hazard proof: STAGE(t+1) overwrites slot (t+1)&1, last read at iter t-1;
// its readers passed iter t-1's trailing barrier (MFMA consumed the reads),
// and STAGE(t+1) issues after that barrier. vmcnt(4) at iter t confirms
// STAGE(t)'s 4 loads (oldest of 8 outstanding); leading barrier then
// publishes all waves' tile-t loads.
// ---------------------------------------------------------------------------
__global__ __launch_bounds__(512, 4) void att_kernel(const u16* __restrict__ Xn,
                                                     const u16* __restrict__ Wn,
                                                     const int* __restrict__ mask,
                                                     u32* __restrict__ top1k,
                                                     float* __restrict__ s)
{
  __shared__ __align__(16) u16 ring[2][2][8192];  // [slot][A|B][16 blocks * 512] = 64 KB

  // bijective XCD chunk swizzle: nwg=1024, 8 XCDs.
  const int orig = blockIdx.x;
  const int wg   = ((orig & 7) << 7) | (orig >> 3);
  const int xb   = wg & 7;        // col tile (0..7)
  const int yb   = wg >> 3;       // row panel (0..127)
  const int row0 = yb << 8, col0 = xb << 8;

  const int tid  = threadIdx.x;
  const int wv   = tid >> 6, lane = tid & 63;
  const int wr   = wv >> 2, wc = wv & 3;           // 2M x 4N wave grid
  const int quad = lane >> 4, lc = lane & 15;

  // staging: wave wv covers rows wv*32..+32 of each operand tile (2 blocks)
  const int srow = wv * 32 + (lane >> 2);
  const int skel = (((lane & 3) ^ ((lane >> 3) & 3)) << 3);
  const u16* gA0 = Xn + (size_t)(row0 + srow) * DIMK + skel;
  const u16* gA1 = gA0 + (size_t)16 * DIMK;
  const u16* gB0 = Wn + (size_t)(col0 + srow) * DIMK + skel;
  const u16* gB1 = gB0 + (size_t)16 * DIMK;

  const int fIntra = lc * 32 + ((quad ^ ((lc >> 1) & 3)) << 3);

  fx4 acc[8][4];
#pragma unroll
  for (int mi = 0; mi < 8; mi++)
#pragma unroll
    for (int ni = 0; ni < 4; ni++)
      acc[mi][ni] = fx4{0.f, 0.f, 0.f, 0.f};

#define STAGE(kt)                                                                \
  do {                                                                           \
    const int ko_ = (kt) << 5;                                                   \
    u16* lA_ = &ring[(kt) & 1][0][wv << 10];                                     \
    u16* lB_ = &ring[(kt) & 1][1][wv << 10];                                     \
    __builtin_amdgcn_global_load_lds((gp_t)(gA0 + ko_), (lp_t)lA_,         16, 0, 0); \
    __builtin_amdgcn_global_load_lds((gp_t)(gA1 + ko_), (lp_t)(lA_ + 512), 16, 0, 0); \
    __builtin_amdgcn_global_load_lds((gp_t)(gB0 + ko_), (lp_t)lB_,         16, 0, 0); \
    __builtin_amdgcn_global_load_lds((gp_t)(gB1 + ko_), (lp_t)(lB_ + 512), 16, 0, 0); \
  } while (0)

  STAGE(0);

  const int NT = DIMK / 32;  // 64
#pragma unroll 1
  for (int t = 0; t < NT; ++t) {
    if (t + 1 < NT) {
      STAGE(t + 1);
      asm volatile("s_waitcnt vmcnt(4)" ::: "memory");  // tile t landed (this wave)
    } else {
      asm volatile("s_waitcnt vmcnt(0)" ::: "memory");
    }
    __builtin_amdgcn_s_barrier();   // all waves' tile-t loads visible

    const u16* lAt = &ring[t & 1][0][0];
    const u16* lBt = &ring[t & 1][1][0];
    short8 bfr[4], af[8];
#pragma unroll
    for (int ni = 0; ni < 4; ni++)
      bfr[ni] = *(const short8*)(lBt + (wc * 4 + ni) * 512 + fIntra);
#pragma unroll
    for (int mi = 0; mi < 8; mi++)
      af[mi] = *(const short8*)(lAt + (wr * 8 + mi) * 512 + fIntra);

    __builtin_amdgcn_s_setprio(1);
#pragma unroll
    for (int mi = 0; mi < 8; mi++)
#pragma unroll
      for (int ni = 0; ni < 4; ni++)
        acc[mi][ni] = __builtin_amdgcn_mfma_f32_16x16x32_bf16(af[mi], bfr[ni], acc[mi][ni], 0, 0, 0);
    __builtin_amdgcn_s_setprio(0);
    __builtin_amdgcn_s_barrier();   // readers done -> slot (t+1)&1 may be overwritten next iter
  }
#undef STAGE

  // ---- epilogue: per-row max over this tile's 256 cols ----
#pragma unroll
  for (int mi = 0; mi < 8; mi++) {
#pragma unroll
    for (int r = 0; r < 4; r++) {
      float v = -3.0e38f;
#pragma unroll
      for (int ni = 0; ni < 4; ni++) {
        int col = col0 + wc * 64 + ni * 16 + lc;
        float av = acc[mi][ni][r];
        v = (col < NBLK && av > v) ? av : v;
      }
      v = fmaxf(v, __shfl_xor(v, 1));
      v = fmaxf(v, __shfl_xor(v, 2));
      v = fmaxf(v, __shfl_xor(v, 4));
      v = fmaxf(v, __shfl_xor(v, 8));
      if (lc == 0) {
        int row = row0 + wr * 128 + mi * 16 + quad * 4 + r;
        atomicMax(&top1k[row], fkey(v));
      }
    }
  }

  // ---- masked column sums for first half-batch -> s[b][col] ----
  if (yb < 64) {
    const int b = yb >> 2;
    float sv[4] = {0.f, 0.f, 0.f, 0.f};
#pragma unroll
    for (int mi = 0; mi < 8; mi++) {
#pragma unroll
      for (int r = 0; r < 4; r++) {
        float mval = (float)mask[row0 + wr * 128 + mi * 16 + quad * 4 + r];
#pragma unroll
        for (int ni = 0; ni < 4; ni++)
          sv[ni] += mval * acc[mi][ni][r];
      }
    }
#pragma unroll
    for (int ni = 0; ni < 4; ni++) {
      float v = sv[ni];
      v += __shfl_xor(v, 16);
      v += __shfl_xor(v, 32);
      int col = col0 + wc * 64 + ni * 16 + lc;
      if (quad == 0 && col < NBLK)
        atomicAdd(&s[b * 2048 + col], v);
    }
  }
}

__global__ __launch_bounds__(256) void softmax_kernel(const float* __restrict__ s,
                                                      float* __restrict__ tmp)
{
  const int b = blockIdx.x, tid = threadIdx.x;
  const float* sb = s + b * 2048;
  __shared__ float red[4];
  float mx = -3.0e38f;
  for (int n = tid; n < NBLK; n += 256) mx = fmaxf(mx, sb[n]);
#pragma unroll
  for (int off = 1; off < 64; off <<= 1) mx = fmaxf(mx, __shfl_xor(mx, off));
  if ((tid & 63) == 0) red[tid >> 6] = mx;
  __syncthreads();
  mx = fmaxf(fmaxf(red[0], red[1]), fmaxf(red[2], red[3]));
  __syncthreads();
  float se = 0.f;
  for (int n = tid; n < NBLK; n += 256) se += expf(sb[n] - mx);
#pragma unroll
  for (int off = 1; off < 64; off <<= 1) se += __shfl_xor(se, off);
  if ((tid & 63) == 0) red[tid >> 6] = se;
  __syncthreads();
  se = red[0] + red[1] + red[2] + red[3];
  float scale = 1.0f / (se * 16.0f);
  for (int n = tid; n < NBLK; n += 256) atomicAdd(&tmp[n], expf(sb[n] - mx) * scale);
}

__global__ __launch_bounds__(1024) void finalize_kernel(const u32* __restrict__ top1k,
                                                        const int* __restrict__ mask,
                                                        const float* __restrict__ tmp,
                                                        const float* __restrict__ divsum,
                                                        float* __restrict__ out)
{
  const int tid = threadIdx.x;
  __shared__ float sMin[32];
  __shared__ float sSq[16];
  const int b = tid >> 5, li = tid & 31;
  float mn = 3.0e38f;
  for (int t = li; t < 1024; t += 32) {
    int idx = b * 1024 + t;
    if (mask[idx] > 0) mn = fminf(mn, dekey(top1k[idx]));
  }
#pragma unroll
  for (int off = 1; off < 32; off <<= 1) mn = fminf(mn, __shfl_xor(mn, off));
  if (li == 0) sMin[b] = mn;
  float ssq = 0.f;
  for (int n = tid; n < NBLK; n += 1024) { float v = tmp[n]; ssq += v * v; }
#pragma unroll
  for (int off = 1; off < 64; off <<= 1) ssq += __shfl_xor(ssq, off);
  if ((tid & 63) == 0) sSq[tid >> 6] = ssq;
  __syncthreads();
  if (tid == 0) {
    float m0 = 0.f, m1 = 0.f;
    for (int i = 0; i < 16; i++) { m0 += sMin[i]; m1 += sMin[16 + i]; }
    m0 *= (1.0f / 16.0f); m1 *= (1.0f / 16.0f);
    float sq = 0.f;
    for (int i = 0; i < 16; i++) sq += sSq[i];
    out[0] = 0.2f * sqrtf(divsum[0]);
    out[1] = 2.0f - m0 + m1;
    out[2] = 0.5f * sqrtf(sq);
  }
}

extern "C" void kernel_launch(void* const* d_in, const int* in_sizes, int n_in,
                              void* d_out, int out_size, void* d_ws, size_t ws_size,
                              hipStream_t stream) {
  const float* x    = (const float*)d_in[0];   // [32,1024,2048] f32
  const int*   mask = (const int*)d_in[1];     // [32,1024] i32
  const float* w    = (const float*)d_in[2];   // [2000,2048] f32
  float* out = (float*)d_out;

  char* ws = (char*)d_ws;
  // layout: [top1k 128KB][s 128KB][tmp 8KB][divsum 256B][Xn 128MB][Wn 8MB][Wb 8MB]
  u32*   top1k  = (u32*)(ws);
  float* s      = (float*)(ws + 131072);
  float* tmp    = (float*)(ws + 262144);
  float* divsum = (float*)(ws + 270336);
  u16*   Xn     = (u16*)(ws + 270592);
  u16*   Wn     = (u16*)(ws + 270592 + 134217728ull);
  u16*   Wb     = (u16*)(ws + 270592 + 134217728ull + 8388608ull);

  hipMemsetAsync(ws, 0, 270592, stream);  // zero accumulators + top1 keys

  norm_rows_w<<<dim3(512), dim3(256), 0, stream>>>(w, Wn, Wb);
  norm_rows_x<<<dim3(8192), dim3(256), 0, stream>>>(x, Xn);
  gram_kernel<<<dim3(16, 16), dim3(256), 0, stream>>>(Wb, divsum);
  att_kernel<<<dim3(1024), dim3(512), 0, stream>>>(Xn, Wn, mask, top1k, s);
  softmax_kernel<<<dim3(16), dim3(256), 0, stream>>>(s, tmp);
  finalize_kernel<<<dim3(1), dim3(1024), 0, stream>>>(top1k, mask, tmp, divsum, out);
}

// Round 5
// 773.679 us; speedup vs baseline: 4.0101x; 4.0101x over previous
//
#include <hip/hip_runtime.h>

typedef unsigned short u16;
typedef unsigned int u32;
typedef __attribute__((ext_vector_type(8))) short short8;
typedef __attribute__((ext_vector_type(8))) u16 ushort8;
typedef __attribute__((ext_vector_type(4))) u16 ushort4_t;
typedef __attribute__((ext_vector_type(4))) float fx4;

#define DIMK 2048
#define NBLK 2000

typedef const __attribute__((address_space(1))) void* gp_t;
typedef __attribute__((address_space(3))) void* lp_t;

__device__ __forceinline__ u16 f2bf(float f) {
  u32 u = __float_as_uint(f);
  u32 r = (u + 0x7fffu + ((u >> 16) & 1u)) >> 16;
  return (u16)r;
}

__device__ __forceinline__ u32 fkey(float f) {
  u32 u = __float_as_uint(f);
  return (u & 0x80000000u) ? ~u : (u | 0x80000000u);
}
__device__ __forceinline__ float dekey(u32 k) {
  u32 u = (k & 0x80000000u) ? (k ^ 0x80000000u) : ~k;
  return __uint_as_float(u);
}

// ---------------------------------------------------------------------------
// 128x128 tile, 4 waves (2x2 of 64x64), 3-slot prefetch ring (48 KB LDS).
// r5 design point (r4 post-mortem): per-wave acc MUST stay at 64 regs so
// ~140 total regs/wave -> 3 waves/SIMD -> 3 blocks/CU co-resident WITHOUT
// spills (r4: launch_bounds(512,4) capped regs at 128 < acc alone -> 8 GB
// scratch traffic, MfmaUtil 4%). Cross-block overlap (m114) supplies the
// LDS||MFMA concurrency that barrier-lockstep forbids within a block.
// Counted-vmcnt ring (r1-verified mechanics, distance 2):
//   iter t: STG(t+2) [12 outstanding]; vmcnt(8) -> tile t landed; barrier;
//   ds_read slot t%3; 16 MFMA/wave; barrier. Tail: vmcnt(4), vmcnt(0).
// Slot hazard: STG(t+2) rewrites slot (t-1)%3; its readers' ds_reads
// completed before iter t-1's trailing barrier (MFMA register-consumed),
// and STG issues after iter t's leading barrier. Zero-conflict XOR granule
// swizzle throughout (SQ_LDS_BANK_CONFLICT == 0 measured on this layout).
// ---------------------------------------------------------------------------
__device__ __forceinline__ void ring_gemm128(const u16* gA0, const u16* gA1,
                                             const u16* gB0, const u16* gB1,
                                             u16 (*ring)[2][4096],
                                             int wv, int wr, int wc, int fIntra,
                                             fx4 acc[4][4])
{
#pragma unroll
  for (int mi = 0; mi < 4; mi++)
#pragma unroll
    for (int ni = 0; ni < 4; ni++)
      acc[mi][ni] = fx4{0.f, 0.f, 0.f, 0.f};

#define STG(kt)                                                                  \
  do {                                                                           \
    const int ko_ = (kt) << 5;                                                   \
    u16* lA_ = &ring[(kt) % 3][0][wv << 10];                                     \
    u16* lB_ = &ring[(kt) % 3][1][wv << 10];                                     \
    __builtin_amdgcn_global_load_lds((gp_t)(gA0 + ko_), (lp_t)lA_,         16, 0, 0); \
    __builtin_amdgcn_global_load_lds((gp_t)(gA1 + ko_), (lp_t)(lA_ + 512), 16, 0, 0); \
    __builtin_amdgcn_global_load_lds((gp_t)(gB0 + ko_), (lp_t)lB_,         16, 0, 0); \
    __builtin_amdgcn_global_load_lds((gp_t)(gB1 + ko_), (lp_t)(lB_ + 512), 16, 0, 0); \
  } while (0)

  STG(0);
  STG(1);

  const int NT = DIMK / 32;  // 64
#pragma unroll 1
  for (int t = 0; t < NT; ++t) {
    if (t + 2 < NT) {
      STG(t + 2);
      asm volatile("s_waitcnt vmcnt(8)" ::: "memory");   // tile t landed (this wave)
    } else if (t + 1 < NT) {
      asm volatile("s_waitcnt vmcnt(4)" ::: "memory");
    } else {
      asm volatile("s_waitcnt vmcnt(0)" ::: "memory");
    }
    __builtin_amdgcn_s_barrier();   // all waves' tile-t loads visible

    const u16* lAt = &ring[t % 3][0][0];
    const u16* lBt = &ring[t % 3][1][0];
    short8 af[4], bfr[4];
#pragma unroll
    for (int ni = 0; ni < 4; ni++)
      bfr[ni] = *(const short8*)(lBt + (wc * 4 + ni) * 512 + fIntra);
#pragma unroll
    for (int mi = 0; mi < 4; mi++)
      af[mi] = *(const short8*)(lAt + (wr * 4 + mi) * 512 + fIntra);

    __builtin_amdgcn_s_setprio(1);
#pragma unroll
    for (int mi = 0; mi < 4; mi++)
#pragma unroll
      for (int ni = 0; ni < 4; ni++)
        acc[mi][ni] = __builtin_amdgcn_mfma_f32_16x16x32_bf16(af[mi], bfr[ni], acc[mi][ni], 0, 0, 0);
    __builtin_amdgcn_s_setprio(0);
    __builtin_amdgcn_s_barrier();   // readers done -> slot (t-1)%3 may be rewritten
  }
#undef STG
}

// one wave per row; block = 4 waves = 4 rows. No LDS, no __syncthreads.
__global__ __launch_bounds__(256) void norm_rows_x(const float* __restrict__ x,
                                                   u16* __restrict__ Xn)
{
  const int wv = threadIdx.x >> 6, lane = threadIdx.x & 63;
  const int row = blockIdx.x * 4 + wv;
  const float4* xr = (const float4*)(x + (size_t)row * DIMK);
  float4 v[8];
  float ss = 0.f;
#pragma unroll
  for (int j = 0; j < 8; j++) {
    v[j] = xr[j * 64 + lane];
    ss += v[j].x*v[j].x + v[j].y*v[j].y + v[j].z*v[j].z + v[j].w*v[j].w;
  }
#pragma unroll
  for (int off = 1; off < 64; off <<= 1) ss += __shfl_xor(ss, off);
  float inv = 1.0f / fmaxf(sqrtf(ss), 1e-12f);
  ushort4_t* o = (ushort4_t*)(Xn + (size_t)row * DIMK);
#pragma unroll
  for (int j = 0; j < 8; j++) {
    ushort4_t t;
    t[0] = f2bf(v[j].x * inv); t[1] = f2bf(v[j].y * inv);
    t[2] = f2bf(v[j].z * inv); t[3] = f2bf(v[j].w * inv);
    o[j * 64 + lane] = t;
  }
}

__global__ __launch_bounds__(256) void norm_rows_w(const float* __restrict__ w,
                                                   u16* __restrict__ Wn,
                                                   u16* __restrict__ Wb)
{
  const int wv = threadIdx.x >> 6, lane = threadIdx.x & 63;
  const int row = blockIdx.x * 4 + wv;
  ushort4_t* on_ = (ushort4_t*)(Wn + (size_t)row * DIMK);
  ushort4_t* ob_ = (ushort4_t*)(Wb + (size_t)row * DIMK);
  if (row < NBLK) {
    const float4* wr_ = (const float4*)(w + (size_t)row * DIMK);
    float4 v[8];
    float ss = 0.f;
#pragma unroll
    for (int j = 0; j < 8; j++) {
      v[j] = wr_[j * 64 + lane];
      ss += v[j].x*v[j].x + v[j].y*v[j].y + v[j].z*v[j].z + v[j].w*v[j].w;
    }
#pragma unroll
    for (int off = 1; off < 64; off <<= 1) ss += __shfl_xor(ss, off);
    float inv = 1.0f / fmaxf(sqrtf(ss), 1e-12f);
#pragma unroll
    for (int j = 0; j < 8; j++) {
      ushort4_t tn, tb;
      tn[0] = f2bf(v[j].x * inv); tn[1] = f2bf(v[j].y * inv);
      tn[2] = f2bf(v[j].z * inv); tn[3] = f2bf(v[j].w * inv);
      tb[0] = f2bf(v[j].x); tb[1] = f2bf(v[j].y);
      tb[2] = f2bf(v[j].z); tb[3] = f2bf(v[j].w);
      on_[j * 64 + lane] = tn;
      ob_[j * 64 + lane] = tb;
    }
  } else {
    ushort4_t z = ushort4_t{0, 0, 0, 0};
#pragma unroll
    for (int j = 0; j < 8; j++) { on_[j * 64 + lane] = z; ob_[j * 64 + lane] = z; }
  }
}

// Gram is symmetric: compute only tiles with by <= bx; off-diagonal tiles
// contribute twice. Blocks with by > bx exit before any barrier.
__global__ __launch_bounds__(256) void gram_kernel(const u16* __restrict__ Wb,
                                                   float* __restrict__ divsum)
{
  const int bx = blockIdx.x, by = blockIdx.y;
  if (by > bx) return;
  __shared__ __align__(16) u16 ring[3][2][4096];
  const int tid = threadIdx.x, wv = tid >> 6, lane = tid & 63;
  const int wr = wv & 1, wc = wv >> 1, quad = lane >> 4, lc = lane & 15;
  const int i0 = by * 128, j0 = bx * 128;

  const int srow = wv * 32 + (lane >> 2);
  const int skel = (((lane & 3) ^ ((lane >> 3) & 3)) << 3);
  const u16* gA0 = Wb + (size_t)(i0 + srow) * DIMK + skel;
  const u16* gA1 = gA0 + (size_t)16 * DIMK;
  const u16* gB0 = Wb + (size_t)(j0 + srow) * DIMK + skel;
  const u16* gB1 = gB0 + (size_t)16 * DIMK;
  const int fIntra = lc * 32 + ((quad ^ ((lc >> 1) & 3)) << 3);

  fx4 acc[4][4];
  ring_gemm128(gA0, gA1, gB0, gB1, ring, wv, wr, wc, fIntra, acc);

  const float mult = (bx == by) ? 1.0f : 2.0f;
  float local = 0.f;
#pragma unroll
  for (int mi = 0; mi < 4; mi++) {
#pragma unroll
    for (int ni = 0; ni < 4; ni++) {
#pragma unroll
      for (int r = 0; r < 4; r++) {
        int i = i0 + wr * 64 + mi * 16 + quad * 4 + r;
        int j = j0 + wc * 64 + ni * 16 + lc;
        float g = acc[mi][ni][r];
        float d = (i == j && i < NBLK) ? 1.0f : 0.0f;
        float e = g - d;
        local += e * e;
      }
    }
  }
  local *= mult;
#pragma unroll
  for (int off = 1; off < 64; off <<= 1) local += __shfl_xor(local, off);
  if (lane == 0) atomicAdd(divsum, local);
}

// att: 128x128 tile, 4 waves, 3-slot ring, 3 blocks/CU target.
// Grid 4096 = 256 row-panels x 16 col-tiles; XCD chunking: 512 consecutive
// work-ids per XCD (bijective: 4096 % 8 == 0); within a chunk col-tile varies
// fastest so the A-panel (512 KB) stays L2-hot and W (8 MB) sweeps L3.
__global__ __launch_bounds__(256) void att_kernel(const u16* __restrict__ Xn,
                                                  const u16* __restrict__ Wn,
                                                  const int* __restrict__ mask,
                                                  u32* __restrict__ top1k,
                                                  float* __restrict__ s)
{
  __shared__ __align__(16) u16 ring[3][2][4096];
  const int orig = blockIdx.x;
  const int wg   = ((orig & 7) << 9) | (orig >> 3);
  const int xb   = wg & 15;       // col tile (0..15)
  const int yb   = wg >> 4;       // row panel (0..255)
  const int row0 = yb << 7, col0 = xb << 7;

  const int tid = threadIdx.x, wv = tid >> 6, lane = tid & 63;
  const int wr = wv & 1, wc = wv >> 1, quad = lane >> 4, lc = lane & 15;

  const int srow = wv * 32 + (lane >> 2);
  const int skel = (((lane & 3) ^ ((lane >> 3) & 3)) << 3);
  const u16* gA0 = Xn + (size_t)(row0 + srow) * DIMK + skel;
  const u16* gA1 = gA0 + (size_t)16 * DIMK;
  const u16* gB0 = Wn + (size_t)(col0 + srow) * DIMK + skel;
  const u16* gB1 = gB0 + (size_t)16 * DIMK;
  const int fIntra = lc * 32 + ((quad ^ ((lc >> 1) & 3)) << 3);

  fx4 acc[4][4];
  ring_gemm128(gA0, gA1, gB0, gB1, ring, wv, wr, wc, fIntra, acc);

  // ---- per-row max over this tile's 128 cols ----
#pragma unroll
  for (int mi = 0; mi < 4; mi++) {
#pragma unroll
    for (int r = 0; r < 4; r++) {
      float v = -3.0e38f;
#pragma unroll
      for (int ni = 0; ni < 4; ni++) {
        int col = col0 + wc * 64 + ni * 16 + lc;
        float av = acc[mi][ni][r];
        v = (col < NBLK && av > v) ? av : v;
      }
      v = fmaxf(v, __shfl_xor(v, 1));
      v = fmaxf(v, __shfl_xor(v, 2));
      v = fmaxf(v, __shfl_xor(v, 4));
      v = fmaxf(v, __shfl_xor(v, 8));
      if (lc == 0) {
        int row = row0 + wr * 64 + mi * 16 + quad * 4 + r;
        atomicMax(&top1k[row], fkey(v));
      }
    }
  }

  // ---- masked column sums for first half-batch -> s[b][col] ----
  if (yb < 128) {
    const int b = yb >> 3;
    float sv[4] = {0.f, 0.f, 0.f, 0.f};
#pragma unroll
    for (int mi = 0; mi < 4; mi++) {
#pragma unroll
      for (int r = 0; r < 4; r++) {
        float mval = (float)mask[row0 + wr * 64 + mi * 16 + quad * 4 + r];
#pragma unroll
        for (int ni = 0; ni < 4; ni++)
          sv[ni] += mval * acc[mi][ni][r];
      }
    }
#pragma unroll
    for (int ni = 0; ni < 4; ni++) {
      float v = sv[ni];
      v += __shfl_xor(v, 16);
      v += __shfl_xor(v, 32);
      int col = col0 + wc * 64 + ni * 16 + lc;
      if (quad == 0 && col < NBLK)
        atomicAdd(&s[b * 2048 + col], v);
    }
  }
}

__global__ __launch_bounds__(256) void softmax_kernel(const float* __restrict__ s,
                                                      float* __restrict__ tmp)
{
  const int b = blockIdx.x, tid = threadIdx.x;
  const float* sb = s + b * 2048;
  __shared__ float red[4];
  float mx = -3.0e38f;
  for (int n = tid; n < NBLK; n += 256) mx = fmaxf(mx, sb[n]);
#pragma unroll
  for (int off = 1; off < 64; off <<= 1) mx = fmaxf(mx, __shfl_xor(mx, off));
  if ((tid & 63) == 0) red[tid >> 6] = mx;
  __syncthreads();
  mx = fmaxf(fmaxf(red[0], red[1]), fmaxf(red[2], red[3]));
  __syncthreads();
  float se = 0.f;
  for (int n = tid; n < NBLK; n += 256) se += expf(sb[n] - mx);
#pragma unroll
  for (int off = 1; off < 64; off <<= 1) se += __shfl_xor(se, off);
  if ((tid & 63) == 0) red[tid >> 6] = se;
  __syncthreads();
  se = red[0] + red[1] + red[2] + red[3];
  float scale = 1.0f / (se * 16.0f);
  for (int n = tid; n < NBLK; n += 256) atomicAdd(&tmp[n], expf(sb[n] - mx) * scale);
}

__global__ __launch_bounds__(1024) void finalize_kernel(const u32* __restrict__ top1k,
                                                        const int* __restrict__ mask,
                                                        const float* __restrict__ tmp,
                                                        const float* __restrict__ divsum,
                                                        float* __restrict__ out)
{
  const int tid = threadIdx.x;
  __shared__ float sMin[32];
  __shared__ float sSq[16];
  const int b = tid >> 5, li = tid & 31;
  float mn = 3.0e38f;
  for (int t = li; t < 1024; t += 32) {
    int idx = b * 1024 + t;
    if (mask[idx] > 0) mn = fminf(mn, dekey(top1k[idx]));
  }
#pragma unroll
  for (int off = 1; off < 32; off <<= 1) mn = fminf(mn, __shfl_xor(mn, off));
  if (li == 0) sMin[b] = mn;
  float ssq = 0.f;
  for (int n = tid; n < NBLK; n += 1024) { float v = tmp[n]; ssq += v * v; }
#pragma unroll
  for (int off = 1; off < 64; off <<= 1) ssq += __shfl_xor(ssq, off);
  if ((tid & 63) == 0) sSq[tid >> 6] = ssq;
  __syncthreads();
  if (tid == 0) {
    float m0 = 0.f, m1 = 0.f;
    for (int i = 0; i < 16; i++) { m0 += sMin[i]; m1 += sMin[16 + i]; }
    m0 *= (1.0f / 16.0f); m1 *= (1.0f / 16.0f);
    float sq = 0.f;
    for (int i = 0; i < 16; i++) sq += sSq[i];
    out[0] = 0.2f * sqrtf(divsum[0]);
    out[1] = 2.0f - m0 + m1;
    out[2] = 0.5f * sqrtf(sq);
  }
}

extern "C" void kernel_launch(void* const* d_in, const int* in_sizes, int n_in,
                              void* d_out, int out_size, void* d_ws, size_t ws_size,
                              hipStream_t stream) {
  const float* x    = (const float*)d_in[0];   // [32,1024,2048] f32
  const int*   mask = (const int*)d_in[1];     // [32,1024] i32
  const float* w    = (const float*)d_in[2];   // [2000,2048] f32
  float* out = (float*)d_out;

  char* ws = (char*)d_ws;
  // layout: [top1k 128KB][s 128KB][tmp 8KB][divsum 256B][Xn 128MB][Wn 8MB][Wb 8MB]
  u32*   top1k  = (u32*)(ws);
  float* s      = (float*)(ws + 131072);
  float* tmp    = (float*)(ws + 262144);
  float* divsum = (float*)(ws + 270336);
  u16*   Xn     = (u16*)(ws + 270592);
  u16*   Wn     = (u16*)(ws + 270592 + 134217728ull);
  u16*   Wb     = (u16*)(ws + 270592 + 134217728ull + 8388608ull);

  hipMemsetAsync(ws, 0, 270592, stream);  // zero accumulators + top1 keys

  norm_rows_w<<<dim3(512), dim3(256), 0, stream>>>(w, Wn, Wb);
  norm_rows_x<<<dim3(8192), dim3(256), 0, stream>>>(x, Xn);
  gram_kernel<<<dim3(16, 16), dim3(256), 0, stream>>>(Wb, divsum);
  att_kernel<<<dim3(4096), dim3(256), 0, stream>>>(Xn, Wn, mask, top1k, s);
  softmax_kernel<<<dim3(16), dim3(256), 0, stream>>>(s, tmp);
  finalize_kernel<<<dim3(1), dim3(1024), 0, stream>>>(top1k, mask, tmp, divsum, out);
}

// Round 6
// 724.681 us; speedup vs baseline: 4.2813x; 1.0676x over previous
//
#include <hip/hip_runtime.h>

typedef unsigned short u16;
typedef unsigned int u32;
typedef __attribute__((ext_vector_type(8))) short short8;
typedef __attribute__((ext_vector_type(8))) u16 ushort8;
typedef __attribute__((ext_vector_type(4))) u16 ushort4_t;
typedef __attribute__((ext_vector_type(4))) float fx4;

#define DIMK 2048
#define NBLK 2000

typedef const __attribute__((address_space(1))) void* gp_t;
typedef __attribute__((address_space(3))) void* lp_t;

__device__ __forceinline__ u16 f2bf(float f) {
  u32 u = __float_as_uint(f);
  u32 r = (u + 0x7fffu + ((u >> 16) & 1u)) >> 16;
  return (u16)r;
}

__device__ __forceinline__ u32 fkey(float f) {
  u32 u = __float_as_uint(f);
  return (u & 0x80000000u) ? ~u : (u | 0x80000000u);
}
__device__ __forceinline__ float dekey(u32 k) {
  u32 u = (k & 0x80000000u) ? (k ^ 0x80000000u) : ~k;
  return __uint_as_float(u);
}

// ---------------------------------------------------------------------------
// 128x128 tile, 4 waves, 3-slot ring (48 KB) — kept for gram_kernel (r5-
// verified). Zero-conflict XOR granule swizzle (SQ_LDS_BANK_CONFLICT == 0).
// ---------------------------------------------------------------------------
__device__ __forceinline__ void ring_gemm128(const u16* gA0, const u16* gA1,
                                             const u16* gB0, const u16* gB1,
                                             u16 (*ring)[2][4096],
                                             int wv, int wr, int wc, int fIntra,
                                             fx4 acc[4][4])
{
#pragma unroll
  for (int mi = 0; mi < 4; mi++)
#pragma unroll
    for (int ni = 0; ni < 4; ni++)
      acc[mi][ni] = fx4{0.f, 0.f, 0.f, 0.f};

#define STG(kt)                                                                  \
  do {                                                                           \
    const int ko_ = (kt) << 5;                                                   \
    u16* lA_ = &ring[(kt) % 3][0][wv << 10];                                     \
    u16* lB_ = &ring[(kt) % 3][1][wv << 10];                                     \
    __builtin_amdgcn_global_load_lds((gp_t)(gA0 + ko_), (lp_t)lA_,         16, 0, 0); \
    __builtin_amdgcn_global_load_lds((gp_t)(gA1 + ko_), (lp_t)(lA_ + 512), 16, 0, 0); \
    __builtin_amdgcn_global_load_lds((gp_t)(gB0 + ko_), (lp_t)lB_,         16, 0, 0); \
    __builtin_amdgcn_global_load_lds((gp_t)(gB1 + ko_), (lp_t)(lB_ + 512), 16, 0, 0); \
  } while (0)

  STG(0);
  STG(1);

  const int NT = DIMK / 32;  // 64
#pragma unroll 1
  for (int t = 0; t < NT; ++t) {
    if (t + 2 < NT) {
      STG(t + 2);
      asm volatile("s_waitcnt vmcnt(8)" ::: "memory");
    } else if (t + 1 < NT) {
      asm volatile("s_waitcnt vmcnt(4)" ::: "memory");
    } else {
      asm volatile("s_waitcnt vmcnt(0)" ::: "memory");
    }
    __builtin_amdgcn_s_barrier();

    const u16* lAt = &ring[t % 3][0][0];
    const u16* lBt = &ring[t % 3][1][0];
    short8 af[4], bfr[4];
#pragma unroll
    for (int ni = 0; ni < 4; ni++)
      bfr[ni] = *(const short8*)(lBt + (wc * 4 + ni) * 512 + fIntra);
#pragma unroll
    for (int mi = 0; mi < 4; mi++)
      af[mi] = *(const short8*)(lAt + (wr * 4 + mi) * 512 + fIntra);

    __builtin_amdgcn_s_setprio(1);
#pragma unroll
    for (int mi = 0; mi < 4; mi++)
#pragma unroll
      for (int ni = 0; ni < 4; ni++)
        acc[mi][ni] = __builtin_amdgcn_mfma_f32_16x16x32_bf16(af[mi], bfr[ni], acc[mi][ni], 0, 0, 0);
    __builtin_amdgcn_s_setprio(0);
    __builtin_amdgcn_s_barrier();
  }
#undef STG
}

// one wave per row; block = 4 waves = 4 rows. No LDS, no __syncthreads.
__global__ __launch_bounds__(256) void norm_rows_x(const float* __restrict__ x,
                                                   u16* __restrict__ Xn)
{
  const int wv = threadIdx.x >> 6, lane = threadIdx.x & 63;
  const int row = blockIdx.x * 4 + wv;
  const float4* xr = (const float4*)(x + (size_t)row * DIMK);
  float4 v[8];
  float ss = 0.f;
#pragma unroll
  for (int j = 0; j < 8; j++) {
    v[j] = xr[j * 64 + lane];
    ss += v[j].x*v[j].x + v[j].y*v[j].y + v[j].z*v[j].z + v[j].w*v[j].w;
  }
#pragma unroll
  for (int off = 1; off < 64; off <<= 1) ss += __shfl_xor(ss, off);
  float inv = 1.0f / fmaxf(sqrtf(ss), 1e-12f);
  ushort4_t* o = (ushort4_t*)(Xn + (size_t)row * DIMK);
#pragma unroll
  for (int j = 0; j < 8; j++) {
    ushort4_t t;
    t[0] = f2bf(v[j].x * inv); t[1] = f2bf(v[j].y * inv);
    t[2] = f2bf(v[j].z * inv); t[3] = f2bf(v[j].w * inv);
    o[j * 64 + lane] = t;
  }
}

__global__ __launch_bounds__(256) void norm_rows_w(const float* __restrict__ w,
                                                   u16* __restrict__ Wn,
                                                   u16* __restrict__ Wb)
{
  const int wv = threadIdx.x >> 6, lane = threadIdx.x & 63;
  const int row = blockIdx.x * 4 + wv;
  ushort4_t* on_ = (ushort4_t*)(Wn + (size_t)row * DIMK);
  ushort4_t* ob_ = (ushort4_t*)(Wb + (size_t)row * DIMK);
  if (row < NBLK) {
    const float4* wr_ = (const float4*)(w + (size_t)row * DIMK);
    float4 v[8];
    float ss = 0.f;
#pragma unroll
    for (int j = 0; j < 8; j++) {
      v[j] = wr_[j * 64 + lane];
      ss += v[j].x*v[j].x + v[j].y*v[j].y + v[j].z*v[j].z + v[j].w*v[j].w;
    }
#pragma unroll
    for (int off = 1; off < 64; off <<= 1) ss += __shfl_xor(ss, off);
    float inv = 1.0f / fmaxf(sqrtf(ss), 1e-12f);
#pragma unroll
    for (int j = 0; j < 8; j++) {
      ushort4_t tn, tb;
      tn[0] = f2bf(v[j].x * inv); tn[1] = f2bf(v[j].y * inv);
      tn[2] = f2bf(v[j].z * inv); tn[3] = f2bf(v[j].w * inv);
      tb[0] = f2bf(v[j].x); tb[1] = f2bf(v[j].y);
      tb[2] = f2bf(v[j].z); tb[3] = f2bf(v[j].w);
      on_[j * 64 + lane] = tn;
      ob_[j * 64 + lane] = tb;
    }
  } else {
    ushort4_t z = ushort4_t{0, 0, 0, 0};
#pragma unroll
    for (int j = 0; j < 8; j++) { on_[j * 64 + lane] = z; ob_[j * 64 + lane] = z; }
  }
}

// Gram is symmetric: only by <= bx tiles; off-diagonal counted twice.
__global__ __launch_bounds__(256) void gram_kernel(const u16* __restrict__ Wb,
                                                   float* __restrict__ divsum)
{
  const int bx = blockIdx.x, by = blockIdx.y;
  if (by > bx) return;
  __shared__ __align__(16) u16 ring[3][2][4096];
  const int tid = threadIdx.x, wv = tid >> 6, lane = tid & 63;
  const int wr = wv & 1, wc = wv >> 1, quad = lane >> 4, lc = lane & 15;
  const int i0 = by * 128, j0 = bx * 128;

  const int srow = wv * 32 + (lane >> 2);
  const int skel = (((lane & 3) ^ ((lane >> 3) & 3)) << 3);
  const u16* gA0 = Wb + (size_t)(i0 + srow) * DIMK + skel;
  const u16* gA1 = gA0 + (size_t)16 * DIMK;
  const u16* gB0 = Wb + (size_t)(j0 + srow) * DIMK + skel;
  const u16* gB1 = gB0 + (size_t)16 * DIMK;
  const int fIntra = lc * 32 + ((quad ^ ((lc >> 1) & 3)) << 3);

  fx4 acc[4][4];
  ring_gemm128(gA0, gA1, gB0, gB1, ring, wv, wr, wc, fIntra, acc);

  const float mult = (bx == by) ? 1.0f : 2.0f;
  float local = 0.f;
#pragma unroll
  for (int mi = 0; mi < 4; mi++) {
#pragma unroll
    for (int ni = 0; ni < 4; ni++) {
#pragma unroll
      for (int r = 0; r < 4; r++) {
        int i = i0 + wr * 64 + mi * 16 + quad * 4 + r;
        int j = j0 + wc * 64 + ni * 16 + lc;
        float g = acc[mi][ni][r];
        float d = (i == j && i < NBLK) ? 1.0f : 0.0f;
        float e = g - d;
        local += e * e;
      }
    }
  }
  local *= mult;
#pragma unroll
  for (int off = 1; off < 64; off <<= 1) local += __shfl_xor(local, off);
  if (lane == 0) atomicAdd(divsum, local);
}

// ---------------------------------------------------------------------------
// att r6: 128x256 tile, 4 waves (2Mx2N, each 64x128), 3-slot ring (72 KB),
// __launch_bounds__(256,2) -> 2 blocks/CU (LDS 144/160 KB, regs ~228<=256).
// Combines r1's 256-wide fragment-reuse ratio (12 ds_read feed 32 MFMA,
// FETCH ~200-300 MB) with r5's cross-block anti-phase overlap (m114) that
// barrier lockstep forbids within a block. acc[4][8] = 128 regs (hard floor,
// r4 spill lesson). Ring mechanics identical to r5 (verified): 6 loads/tile,
// distance 2, steady vmcnt(12), tail vmcnt(6)/vmcnt(0); slot rewrite at
// distance 2 protected by the trailing barrier (readers' MFMA issue implies
// ds_read completion before barrier arrival).
// Grid 2048 = 256 row-panels x 8 col-tiles; 2-level XCD chunking: each XCD
// gets 32 consecutive panels x 8 cols, iterated as 4-panel x 8-col subgroups
// so A-group (2 MB) + B-tile (1 MB) stay L2-resident.
// ---------------------------------------------------------------------------
__global__ __launch_bounds__(256, 2) void att_kernel(const u16* __restrict__ Xn,
                                                     const u16* __restrict__ Wn,
                                                     const int* __restrict__ mask,
                                                     u32* __restrict__ top1k,
                                                     float* __restrict__ s)
{
  __shared__ __align__(16) u16 ring[3][12288];  // [slot][A:0..4095 | B:4096..12287]

  const int orig  = blockIdx.x;
  const int xcd   = orig & 7;
  const int local = orig >> 3;                  // 0..255
  const int yb    = xcd * 32 + ((local >> 5) << 2) + (local & 3);  // row panel 0..255
  const int xb    = (local >> 2) & 7;                              // col tile 0..7
  const int row0 = yb << 7, col0 = xb << 8;

  const int tid = threadIdx.x, wv = tid >> 6, lane = tid & 63;
  const int wr = wv >> 1, wc = wv & 1, quad = lane >> 4, lc = lane & 15;

  // staging: wave wv stages A rows wv*32..+32 (2 blocks) and B rows wv*64..+64 (4 blocks)
  const int srow = lane >> 2;
  const int skel = (((lane & 3) ^ ((lane >> 3) & 3)) << 3);
  const u16* gA0 = Xn + (size_t)(row0 + wv * 32 + srow) * DIMK + skel;
  const u16* gA1 = gA0 + (size_t)16 * DIMK;
  const u16* gB0 = Wn + (size_t)(col0 + wv * 64 + srow) * DIMK + skel;
  const u16* gB1 = gB0 + (size_t)16 * DIMK;
  const u16* gB2 = gB0 + (size_t)32 * DIMK;
  const u16* gB3 = gB0 + (size_t)48 * DIMK;
  const int fIntra = lc * 32 + ((quad ^ ((lc >> 1) & 3)) << 3);

  fx4 acc[4][8];
#pragma unroll
  for (int mi = 0; mi < 4; mi++)
#pragma unroll
    for (int ni = 0; ni < 8; ni++)
      acc[mi][ni] = fx4{0.f, 0.f, 0.f, 0.f};

#define STG6(kt)                                                                 \
  do {                                                                           \
    const int ko_ = (kt) << 5;                                                   \
    u16* lA_ = &ring[(kt) % 3][wv << 10];                                        \
    u16* lB_ = &ring[(kt) % 3][4096 + (wv << 11)];                               \
    __builtin_amdgcn_global_load_lds((gp_t)(gA0 + ko_), (lp_t)lA_,          16, 0, 0); \
    __builtin_amdgcn_global_load_lds((gp_t)(gA1 + ko_), (lp_t)(lA_ + 512),  16, 0, 0); \
    __builtin_amdgcn_global_load_lds((gp_t)(gB0 + ko_), (lp_t)lB_,          16, 0, 0); \
    __builtin_amdgcn_global_load_lds((gp_t)(gB1 + ko_), (lp_t)(lB_ + 512),  16, 0, 0); \
    __builtin_amdgcn_global_load_lds((gp_t)(gB2 + ko_), (lp_t)(lB_ + 1024), 16, 0, 0); \
    __builtin_amdgcn_global_load_lds((gp_t)(gB3 + ko_), (lp_t)(lB_ + 1536), 16, 0, 0); \
  } while (0)

  STG6(0);
  STG6(1);

  const int NT = DIMK / 32;  // 64
#pragma unroll 1
  for (int t = 0; t < NT; ++t) {
    if (t + 2 < NT) {
      STG6(t + 2);
      asm volatile("s_waitcnt vmcnt(12)" ::: "memory");  // tile t landed (this wave)
    } else if (t + 1 < NT) {
      asm volatile("s_waitcnt vmcnt(6)" ::: "memory");
    } else {
      asm volatile("s_waitcnt vmcnt(0)" ::: "memory");
    }
    __builtin_amdgcn_s_barrier();   // all waves' tile-t loads visible

    const u16* lAt = &ring[t % 3][0];
    const u16* lBt = &ring[t % 3][0] + 4096;
    short8 af[4], bfr[8];
#pragma unroll
    for (int ni = 0; ni < 8; ni++)
      bfr[ni] = *(const short8*)(lBt + (wc * 8 + ni) * 512 + fIntra);
#pragma unroll
    for (int mi = 0; mi < 4; mi++)
      af[mi] = *(const short8*)(lAt + (wr * 4 + mi) * 512 + fIntra);

    __builtin_amdgcn_s_setprio(1);
#pragma unroll
    for (int mi = 0; mi < 4; mi++)
#pragma unroll
      for (int ni = 0; ni < 8; ni++)
        acc[mi][ni] = __builtin_amdgcn_mfma_f32_16x16x32_bf16(af[mi], bfr[ni], acc[mi][ni], 0, 0, 0);
    __builtin_amdgcn_s_setprio(0);
    __builtin_amdgcn_s_barrier();   // readers done -> slot (t+2)%3 rewrite safe
  }
#undef STG6

  // ---- per-row max over this tile's 256 cols ----
#pragma unroll
  for (int mi = 0; mi < 4; mi++) {
#pragma unroll
    for (int r = 0; r < 4; r++) {
      float v = -3.0e38f;
#pragma unroll
      for (int ni = 0; ni < 8; ni++) {
        int col = col0 + wc * 128 + ni * 16 + lc;
        float av = acc[mi][ni][r];
        v = (col < NBLK && av > v) ? av : v;
      }
      v = fmaxf(v, __shfl_xor(v, 1));
      v = fmaxf(v, __shfl_xor(v, 2));
      v = fmaxf(v, __shfl_xor(v, 4));
      v = fmaxf(v, __shfl_xor(v, 8));
      if (lc == 0) {
        int row = row0 + wr * 64 + mi * 16 + quad * 4 + r;
        atomicMax(&top1k[row], fkey(v));
      }
    }
  }

  // ---- masked column sums for first half-batch -> s[b][col] ----
  if (yb < 128) {
    const int b = yb >> 3;
    float sv[8] = {0.f, 0.f, 0.f, 0.f, 0.f, 0.f, 0.f, 0.f};
#pragma unroll
    for (int mi = 0; mi < 4; mi++) {
#pragma unroll
      for (int r = 0; r < 4; r++) {
        float mval = (float)mask[row0 + wr * 64 + mi * 16 + quad * 4 + r];
#pragma unroll
        for (int ni = 0; ni < 8; ni++)
          sv[ni] += mval * acc[mi][ni][r];
      }
    }
#pragma unroll
    for (int ni = 0; ni < 8; ni++) {
      float v = sv[ni];
      v += __shfl_xor(v, 16);
      v += __shfl_xor(v, 32);
      int col = col0 + wc * 128 + ni * 16 + lc;
      if (quad == 0 && col < NBLK)
        atomicAdd(&s[b * 2048 + col], v);
    }
  }
}

// softmax + finalize merged: one block, 16 waves. Eliminates the tmp buffer,
// 32k global atomics, and one kernel launch.
__global__ __launch_bounds__(1024) void tail_kernel(const float* __restrict__ s,
                                                    const u32* __restrict__ top1k,
                                                    const int* __restrict__ mask,
                                                    const float* __restrict__ divsum,
                                                    float* __restrict__ out)
{
  const int tid = threadIdx.x;
  const int w = tid >> 6, lane = tid & 63;     // 16 waves, wave w -> softmax row w
  __shared__ float mx_s[16], ise_s[16];
  __shared__ float red[16];
  __shared__ float sMin[32];

  // phase 1: per-row max and sum-exp
  const float* sb = s + w * 2048;
  float mx = -3.0e38f;
  for (int n = lane; n < NBLK; n += 64) mx = fmaxf(mx, sb[n]);
#pragma unroll
  for (int off = 1; off < 64; off <<= 1) mx = fmaxf(mx, __shfl_xor(mx, off));
  float se = 0.f;
  for (int n = lane; n < NBLK; n += 64) se += expf(sb[n] - mx);
#pragma unroll
  for (int off = 1; off < 64; off <<= 1) se += __shfl_xor(se, off);
  if (lane == 0) { mx_s[w] = mx; ise_s[w] = 1.0f / (se * 16.0f); }
  __syncthreads();

  // phase 2: column means of softmax -> sum of squares
  float ssq = 0.f;
  for (int n = tid; n < NBLK; n += 1024) {
    float v = 0.f;
#pragma unroll
    for (int b = 0; b < 16; b++)
      v += expf(s[b * 2048 + n] - mx_s[b]) * ise_s[b];
    ssq += v * v;
  }
#pragma unroll
  for (int off = 1; off < 64; off <<= 1) ssq += __shfl_xor(ssq, off);
  if (lane == 0) red[w] = ssq;

  // phase 3 (independent of 1-2): per-batch-row min of masked top1
  const int b = tid >> 5, li = tid & 31;
  float mn = 3.0e38f;
  for (int t = li; t < 1024; t += 32) {
    int idx = b * 1024 + t;
    if (mask[idx] > 0) mn = fminf(mn, dekey(top1k[idx]));
  }
#pragma unroll
  for (int off = 1; off < 32; off <<= 1) mn = fminf(mn, __shfl_xor(mn, off));
  if (li == 0) sMin[b] = mn;
  __syncthreads();

  if (tid == 0) {
    float m0 = 0.f, m1 = 0.f;
    for (int i = 0; i < 16; i++) { m0 += sMin[i]; m1 += sMin[16 + i]; }
    m0 *= (1.0f / 16.0f); m1 *= (1.0f / 16.0f);
    float sq = 0.f;
    for (int i = 0; i < 16; i++) sq += red[i];
    out[0] = 0.2f * sqrtf(divsum[0]);
    out[1] = 2.0f - m0 + m1;
    out[2] = 0.5f * sqrtf(sq);
  }
}

extern "C" void kernel_launch(void* const* d_in, const int* in_sizes, int n_in,
                              void* d_out, int out_size, void* d_ws, size_t ws_size,
                              hipStream_t stream) {
  const float* x    = (const float*)d_in[0];   // [32,1024,2048] f32
  const int*   mask = (const int*)d_in[1];     // [32,1024] i32
  const float* w    = (const float*)d_in[2];   // [2000,2048] f32
  float* out = (float*)d_out;

  char* ws = (char*)d_ws;
  // layout: [top1k 128KB][s 128KB][tmp 8KB unused][divsum 256B][Xn 128MB][Wn 8MB][Wb 8MB]
  u32*   top1k  = (u32*)(ws);
  float* s      = (float*)(ws + 131072);
  float* divsum = (float*)(ws + 270336);
  u16*   Xn     = (u16*)(ws + 270592);
  u16*   Wn     = (u16*)(ws + 270592 + 134217728ull);
  u16*   Wb     = (u16*)(ws + 270592 + 134217728ull + 8388608ull);

  hipMemsetAsync(ws, 0, 270592, stream);  // zero accumulators + top1 keys

  norm_rows_w<<<dim3(512), dim3(256), 0, stream>>>(w, Wn, Wb);
  norm_rows_x<<<dim3(8192), dim3(256), 0, stream>>>(x, Xn);
  gram_kernel<<<dim3(16, 16), dim3(256), 0, stream>>>(Wb, divsum);
  att_kernel<<<dim3(2048), dim3(256), 0, stream>>>(Xn, Wn, mask, top1k, s);
  tail_kernel<<<dim3(1), dim3(1024), 0, stream>>>(s, top1k, mask, divsum, out);
}